// Round 1
// baseline (82.819 us; speedup 1.0000x reference)
//
#include <hip/hip_runtime.h>
#include <math.h>

// RotationDiffuser score (MI355X/gfx950) — R13: trim f64, 2-chain series, vec staging.
// LOCKED (byte-identical to R10-R12 pass, absmax 0.03125):
//   FMA-contracted dots, tr, cosv, clip, theta (f64 acos polys),
//   st (f64 sin poly), v, ssum, gf algebra, exp_d coef table.
// R13 changes:
//   * scale: native f32 IEEE div (CR; replaces f64 div + round = double rounding)
//   * w: native f32 IEEE sqrt (CR; feeds only 1e-3-tol series and smooth 1/(w+eps))
//   * series: TWO independent (s,c) chains stepping 2w (half dep latency),
//     float4 coef table {c0,c0h,c1,c1h} -> one ds_read_b128 per 2 l's
//   * staging: float4 global->LDS (4.5 ld/thread vs 18), float4 output store

#define BD 256
#define LMAX 100

__device__ __forceinline__ float opq(float x) { __asm__("" : "+v"(x)); return x; }
__device__ __forceinline__ float MULF(float a, float b) { return opq(a * b); }
__device__ __forceinline__ float ADDF(float a, float b) { return opq(a + b); }
__device__ __forceinline__ float SUBF(float a, float b) { return opq(a - b); }
__device__ __forceinline__ float FMAF(float a, float b, float c) { return opq(__builtin_fmaf(a, b, c)); }
__device__ __forceinline__ float DOT3F(float a0, float b0, float a1, float b1,
                                       float a2, float b2) {
    return FMAF(a2, b2, FMAF(a1, b1, MULF(a0, b0)));
}

// ---- f64 polys (locked path: theta, st) ----
__device__ __forceinline__ double asin_p(double u) {     // asin(t)/t, u=t^2<=0.25
    double p = 0.00515311;
    p = __builtin_fma(p, u, 0.00574004);
    p = __builtin_fma(p, u, 0.0064472);
    p = __builtin_fma(p, u, 0.007312526);
    p = __builtin_fma(p, u, 0.008390335809616815);
    p = __builtin_fma(p, u, 0.009761609529194078);
    p = __builtin_fma(p, u, 0.011551800896139706);
    p = __builtin_fma(p, u, 0.01396484375);
    p = __builtin_fma(p, u, 0.017352764423076924);
    p = __builtin_fma(p, u, 0.022372159090909092);
    p = __builtin_fma(p, u, 0.030381944444444444);
    p = __builtin_fma(p, u, 0.044642857142857144);
    p = __builtin_fma(p, u, 0.075);
    p = __builtin_fma(p, u, 0.16666666666666666);
    p = __builtin_fma(p, u, 1.0);
    return p;
}
__device__ __forceinline__ double sin_pd(double u) {     // sin(x)/x, x in [0,pi/2]
    double p = 2.8114572543455206e-15;
    p = __builtin_fma(p, u, -7.647163731819816e-13);
    p = __builtin_fma(p, u, 1.6059043836821613e-10);
    p = __builtin_fma(p, u, -2.505210838544172e-8);
    p = __builtin_fma(p, u, 2.7557319223985893e-6);
    p = __builtin_fma(p, u, -1.984126984126984e-4);
    p = __builtin_fma(p, u, 8.333333333333333e-3);
    p = __builtin_fma(p, u, -0.16666666666666666);
    p = __builtin_fma(p, u, 1.0);
    return p;
}
// ---- f32 polys (series seeds; ~1e-8 rel on [0, pi/2]) ----
__device__ __forceinline__ float sin_pf(float u) {       // sin(x)/x
    float p = -2.5052108e-8f;
    p = __builtin_fmaf(p, u, 2.75573192e-6f);
    p = __builtin_fmaf(p, u, -1.98412698e-4f);
    p = __builtin_fmaf(p, u, 8.33333333e-3f);
    p = __builtin_fmaf(p, u, -0.166666667f);
    p = __builtin_fmaf(p, u, 1.0f);
    return p;
}
__device__ __forceinline__ float cos_pf(float u) {       // cos(x)
    float p = 2.08767570e-9f;
    p = __builtin_fmaf(p, u, -2.75573192e-7f);
    p = __builtin_fmaf(p, u, 2.48015873e-5f);
    p = __builtin_fmaf(p, u, -1.38888889e-3f);
    p = __builtin_fmaf(p, u, 4.16666667e-2f);
    p = __builtin_fmaf(p, u, -0.5f);
    p = __builtin_fmaf(p, u, 1.0f);
    return p;
}
// exp(x) for x<=0; returns 0 for x<-110 (coef rounds to f32 0 there anyway)
__device__ __forceinline__ double exp_d(double x) {
    if (x < -110.0) return 0.0;
    double n = __builtin_rint(x * 1.4426950408889634);
    double r = __builtin_fma(-n, 6.93147180369123816490e-01, x);
    r = __builtin_fma(-n, 1.90821492927058770002e-10, r);
    double p = 2.08767569878681e-9;
    p = __builtin_fma(p, r, 2.505210838544172e-8);
    p = __builtin_fma(p, r, 2.755731922398589e-7);
    p = __builtin_fma(p, r, 2.48015873015873e-5);
    p = __builtin_fma(p, r, 1.984126984126984e-4);
    p = __builtin_fma(p, r, 1.3888888888888889e-3);
    p = __builtin_fma(p, r, 8.333333333333333e-3);
    p = __builtin_fma(p, r, 0.041666666666666664);
    p = __builtin_fma(p, r, 0.16666666666666666);
    p = __builtin_fma(p, r, 0.5);
    p = __builtin_fma(p, r, 1.0);
    p = __builtin_fma(p, r, 1.0);
    long long ni = (long long)n;                       // in [-159, 0]
    double p2 = __longlong_as_double((1023ll + ni) << 52);
    return p * p2;
}

__global__ __launch_bounds__(BD) void rot_score_kernel(
    const float* __restrict__ rt, const float* __restrict__ rh,
    const float* __restrict__ sigma_t, float* __restrict__ out, int npts)
{
    __shared__ __align__(16) float sA[BD * 9];
    __shared__ __align__(16) float sB[BD * 9];
    __shared__ float4 sC4[(LMAX + 2) / 2];             // {c(2j), c(2j)h, c(2j+1), c(2j+1)h}

    const int tid = threadIdx.x;
    const int blocksPerB = npts / BD;
    const int b = blockIdx.x / blocksPerB;
    const size_t base = (size_t)blockIdx.x * BD;

    const float sigma = sigma_t[b];
    const float s2 = MULF(sigma, sigma);

    // ---- float4 staging: 576 float4 per array, 256 threads ----
    const float4* gA4 = reinterpret_cast<const float4*>(rt + base * 9);
    const float4* gB4 = reinterpret_cast<const float4*>(rh + base * 9);
    float4* sA4 = reinterpret_cast<float4*>(sA);
    float4* sB4 = reinterpret_cast<float4*>(sB);
    sA4[tid]      = gA4[tid];
    sA4[tid + BD] = gA4[tid + BD];
    sB4[tid]      = gB4[tid];
    sB4[tid + BD] = gB4[tid + BD];
    if (tid < 64) {
        sA4[tid + 2 * BD] = gA4[tid + 2 * BD];
        sB4[tid + 2 * BD] = gB4[tid + 2 * BD];
    }
    if (tid <= LMAX + 1) {                             // tid==101 -> coef exactly 0
        float lf = (float)tid;
        float t  = MULF(MULF(-lf, lf + 1.0f), s2);
        float arg = t * 0.5f;
        float e  = (float)exp_d((double)arg);          // CR expf equivalent
        float cf = MULF(2.0f * lf + 1.0f, e);
        ((float2*)sC4)[tid] = make_float2(cf, cf * (lf + 0.5f));
    }
    __syncthreads();

    const int o = tid * 9;
    float a0 = sA[o+0], a1 = sA[o+1], a2 = sA[o+2];
    float a3 = sA[o+3], a4 = sA[o+4], a5 = sA[o+5];
    float a6 = sA[o+6], a7 = sA[o+7], a8 = sA[o+8];
    float b0 = sB[o+0], b1 = sB[o+1], b2 = sB[o+2];
    float b3 = sB[o+3], b4 = sB[o+4], b5 = sB[o+5];
    float b6 = sB[o+6], b7 = sB[o+7], b8 = sB[o+8];

    // ---- LOCKED: FMA-contracted dots (= ref einsum semantics) ----
    float m00 = DOT3F(a0,b0, a1,b1, a2,b2);
    float m11 = DOT3F(a3,b3, a4,b4, a5,b5);
    float m22 = DOT3F(a6,b6, a7,b7, a8,b8);
    float m01 = DOT3F(a0,b3, a1,b4, a2,b5);
    float m10 = DOT3F(a3,b0, a4,b1, a5,b2);
    float m02 = DOT3F(a0,b6, a1,b7, a2,b8);
    float m20 = DOT3F(a6,b0, a7,b1, a8,b2);
    float m12 = DOT3F(a3,b6, a4,b7, a5,b8);
    float m21 = DOT3F(a6,b3, a7,b4, a8,b5);

    float tr   = ADDF(ADDF(m00, m11), m22);
    float cosv = MULF(SUBF(tr, 1.0f), 0.5f);
    const float CLO = (float)(-1.0 + 1e-7);
    const float CHI = (float)( 1.0 - 1e-7);
    cosv = fminf(fmaxf(cosv, CLO), CHI);

    // ---- LOCKED: theta via f64 domain-split polys ----
    double xd = (double)cosv;
    double axd = fabs(xd);
    bool mid = (axd <= 0.5);
    double uedge = (1.0 - axd) * 0.5;
    double m = mid ? xd : sqrt(uedge);
    double asv = m * asin_p(m * m);
    double th_mid  = 1.5707963267948966 - asv;
    double th_edge = (xd > 0.0) ? (2.0 * asv)
                                : (3.141592653589793 - 2.0 * asv);
    double theta_d = mid ? th_mid : th_edge;
    float theta = (float)theta_d;

    // ---- LOCKED: st = CR sinf(theta); scale = CR f32 div (native IEEE) ----
    double td = (double)theta;
    double e  = (td > 1.5707963267948966) ? (3.141592653589793 - td) : td;
    float st  = (float)(e * sin_pd(e * e));
    float scale = theta / (2.0f * st);                 // IEEE f32 div = CR
    float ax = SUBF(m21, m12);
    float ay = SUBF(m02, m20);
    float az = SUBF(m10, m01);
    float vx = MULF(ax, scale);
    float vy = MULF(ay, scale);
    float vz = MULF(az, scale);
    float ssum = ADDF(ADDF(MULF(vx,vx), MULF(vy,vy)), MULF(vz,vz));
    float w = sqrtf(ssum);                             // IEEE f32 sqrt = CR

    // ---- series: all f32, two independent chains stepping 2w ----
    float wh = 0.5f * w;
    float u  = wh * wh;
    float sh = wh * sin_pf(u);                         // sin(w/2)
    float ch = cos_pf(u);                              // cos(w/2)
    float sw = 2.0f * sh * ch;                         // sin(w)
    float cw = __builtin_fmaf(-2.0f * sh, sh, 1.0f);   // cos(w)
    float s2w = 2.0f * sw * cw;                        // sin(2w)
    float c2w = __builtin_fmaf(-2.0f * sw, sw, 1.0f);  // cos(2w)

    // uniform trip count: coef==0 beyond l(l+1) > 220/s2 (exp_d clamp)
    int nl = (int)ceilf((-1.0f + sqrtf(1.0f + 880.0f / s2)) * 0.5f) + 1;
    if (nl > LMAX + 1) nl = LMAX + 1;
    int nh = (nl + 1) >> 1;                            // pairs; extra term has coef==0

    float sa = sh, ca = ch;                            // chain A: l even, sin/cos((l+.5)w)
    float sb = __builtin_fmaf(sh, cw,   ch * sw);      // chain B: l odd, sin(1.5w)
    float cb = __builtin_fmaf(ch, cw, -(sh * sw));     //                cos(1.5w)
    float S1a = 0.0f, S2a = 0.0f, S1b = 0.0f, S2b = 0.0f;
#pragma unroll 2
    for (int j = 0; j < nh; ++j) {
        float4 q = sC4[j];                             // one ds_read_b128 (broadcast)
        S1a = __builtin_fmaf(q.x, sa, S1a);
        S2a = __builtin_fmaf(q.y, ca, S2a);
        S1b = __builtin_fmaf(q.z, sb, S1b);
        S2b = __builtin_fmaf(q.w, cb, S2b);
        float nsa = __builtin_fmaf(sa, c2w,   ca * s2w);
        float nca = __builtin_fmaf(ca, c2w, -(sa * s2w));
        float nsb = __builtin_fmaf(sb, c2w,   cb * s2w);
        float ncb = __builtin_fmaf(cb, c2w, -(sb * s2w));
        sa = nsa; ca = nca; sb = nsb; cb = ncb;
    }
    float S1 = S1a + S1b;
    float S2 = S2a + S2b;

    // g = df/((f+eps)(w+eps)) with df=(S2*sh-.5*ch*S1)/sh^2, f=S1/sh
    //   = (S2*sh - .5*ch*S1) / ((sh*S1 + eps*sh^2)*(w+eps))   — ONE f32 div
    float num = __builtin_fmaf(S2, sh, -(0.5f * ch * S1));
    float den = __builtin_fmaf(sh, S1, 1e-12f * sh * sh) * (w + 1e-12f);
    float gf  = num / den;

    float ox, oy, oz;
    if (sigma > 0.6f) {
        ox = vx * gf; oy = vy * gf; oz = vz * gf;
    } else {
        float gi = -1.0f / s2;
        ox = vx * gi; oy = vy * gi; oz = vz * gi;
    }

    __syncthreads();
    sA[tid * 3 + 0] = ox;
    sA[tid * 3 + 1] = oy;
    sA[tid * 3 + 2] = oz;
    __syncthreads();
    if (tid < (BD * 3) / 4) {                          // 192 float4 = 768 floats
        float4* gO4 = reinterpret_cast<float4*>(out + base * 3);
        gO4[tid] = reinterpret_cast<const float4*>(sA)[tid];
    }
}

extern "C" void kernel_launch(void* const* d_in, const int* in_sizes, int n_in,
                              void* d_out, int out_size, void* d_ws, size_t ws_size,
                              hipStream_t stream) {
    const float* r_t     = (const float*)d_in[0];
    const float* rh_0    = (const float*)d_in[1];
    const float* sigma_t = (const float*)d_in[2];
    float* out = (float*)d_out;

    const int nB = in_sizes[2];
    const int n_elem = in_sizes[0] / 9;
    const int npts = n_elem / nB;
    const int grid = n_elem / BD;

    rot_score_kernel<<<grid, BD, 0, stream>>>(r_t, rh_0, sigma_t, out, npts);
}